// Round 1
// 829.732 us; speedup vs baseline: 1.0241x; 1.0241x over previous
//
#include <hip/hip_runtime.h>
#include <math.h>

// SkipGram loss: ragged embedding-bag means + log-sigmoid scoring.
//
// v2: latency-oriented rewrite.
//  - ONE 64-lane wave per bag-row (lane owns dims [2*lane, 2*lane+2) as float2;
//    one gathered table row = 64 lanes x 8B = 512B, still fully coalesced).
//  - All lengths/indices are wave-uniform -> readfirstlane into SGPRs:
//    gathers become global_load_dwordx2 v, v_laneoff, s[base] (scalar addressing),
//    and the "l < len" guards are scalar branches (no exec-mask games).
//  - All 7 bags (1 u + 1 pos_v + 5 neg_v) fully unrolled with predication into
//    separate float2 temps, summed only at the end -> up to ~28 gathers in
//    flight per wave instead of ~1-2 (the old runtime-trip-count loops forced
//    load->add->load serialization).

constexpr int NROWS = 40960;   // BATCH * 2 * WINDOW
constexpr int NEG   = 5;
constexpr int LMAX  = 4;
constexpr int D2    = 64;      // DIM/2 (float2 elements per table row)
constexpr int MAIN_BLOCKS = NROWS / 4;  // 4 waves (= 4 rows) per 256-thread block

__device__ __forceinline__ float log_sigmoidf(float x) {
    // stable: min(x,0) - log1p(exp(-|x|))
    return fminf(x, 0.0f) - log1pf(__expf(-fabsf(x)));
}

__device__ __forceinline__ int rfl(int x) { return __builtin_amdgcn_readfirstlane(x); }

__global__ __launch_bounds__(256, 4) void skipgram_main(
    const float2* __restrict__ u_table,
    const float2* __restrict__ v_table,
    const int*  __restrict__ pos_u_idx,
    const int*  __restrict__ pos_u_len,
    const int*  __restrict__ pos_v_idx,
    const int*  __restrict__ pos_v_len,
    const int*  __restrict__ neg_v_idx,
    const int*  __restrict__ neg_v_len,
    float* __restrict__ block_sums)
{
    const int lane = threadIdx.x & 63;
    const int row  = rfl((int)(blockIdx.x * 4 + (threadIdx.x >> 6)));

    // ---- wave-uniform lengths (SGPRs) ----
    const int lu = rfl(pos_u_len[row]);
    int vlen[6];                       // bag 0 = pos_v, bags 1..5 = neg k
    vlen[0] = rfl(pos_v_len[row]);
    {
        const int* nl = neg_v_len + row * NEG;
        #pragma unroll
        for (int k = 0; k < NEG; ++k) vlen[k + 1] = rfl(nl[k]);
    }

    // ---- wave-uniform indices (SGPRs); idx rows are 16B-aligned int4 ----
    int ui[LMAX];
    {
        int4 t = *(const int4*)(pos_u_idx + row * LMAX);
        ui[0] = rfl(t.x); ui[1] = rfl(t.y); ui[2] = rfl(t.z); ui[3] = rfl(t.w);
    }
    int vi[6][LMAX];
    {
        int4 t = *(const int4*)(pos_v_idx + row * LMAX);
        vi[0][0] = rfl(t.x); vi[0][1] = rfl(t.y); vi[0][2] = rfl(t.z); vi[0][3] = rfl(t.w);
        #pragma unroll
        for (int k = 0; k < NEG; ++k) {
            int4 n = *(const int4*)(neg_v_idx + (row * NEG + k) * LMAX);
            vi[k+1][0] = rfl(n.x); vi[k+1][1] = rfl(n.y);
            vi[k+1][2] = rfl(n.z); vi[k+1][3] = rfl(n.w);
        }
    }

    // ---- embed_u: up to 4 gathers, issued back-to-back (len >= 1 always) ----
    const float2 z = make_float2(0.f, 0.f);
    float2 u0 = u_table[(size_t)ui[0] * D2 + lane];
    float2 u1 = z, u2 = z, u3 = z;
    if (lu > 1) u1 = u_table[(size_t)ui[1] * D2 + lane];
    if (lu > 2) u2 = u_table[(size_t)ui[2] * D2 + lane];
    if (lu > 3) u3 = u_table[(size_t)ui[3] * D2 + lane];

    // ---- v-side: 6 bags x up to 4 gathers, ALL issued before any use ----
    float2 t[6][LMAX];
    #pragma unroll
    for (int b = 0; b < 6; ++b) {
        t[b][1] = z; t[b][2] = z; t[b][3] = z;
        t[b][0] = v_table[(size_t)vi[b][0] * D2 + lane];
        if (vlen[b] > 1) t[b][1] = v_table[(size_t)vi[b][1] * D2 + lane];
        if (vlen[b] > 2) t[b][2] = v_table[(size_t)vi[b][2] * D2 + lane];
        if (vlen[b] > 3) t[b][3] = v_table[(size_t)vi[b][3] * D2 + lane];
    }

    // ---- mean(u), then per-bag dot partials ----
    const float inv_lu = 1.0f / (float)lu;
    const float eux = (u0.x + u1.x + u2.x + u3.x) * inv_lu;
    const float euy = (u0.y + u1.y + u2.y + u3.y) * inv_lu;

    float p[6];
    #pragma unroll
    for (int b = 0; b < 6; ++b) {
        const float sx = t[b][0].x + t[b][1].x + t[b][2].x + t[b][3].x;
        const float sy = t[b][0].y + t[b][1].y + t[b][2].y + t[b][3].y;
        p[b] = (eux * sx + euy * sy) / (float)vlen[b];
    }

    // ---- 6 interleaved 64-lane butterflies ----
    #pragma unroll
    for (int off = 32; off > 0; off >>= 1) {
        #pragma unroll
        for (int b = 0; b < 6; ++b) p[b] += __shfl_xor(p[b], off);
    }

    float term = log_sigmoidf(p[0]);
    #pragma unroll
    for (int b = 1; b < 6; ++b) term += log_sigmoidf(-p[b]);

    // term is wave-uniform; LDS-reduce the block's 4 waves.
    __shared__ float lds[4];
    if (lane == 0) lds[threadIdx.x >> 6] = term;
    __syncthreads();
    if (threadIdx.x == 0)
        block_sums[blockIdx.x] = lds[0] + lds[1] + lds[2] + lds[3];
}

__global__ __launch_bounds__(256) void skipgram_reduce(
    const float* __restrict__ block_sums,
    const int*   __restrict__ batch_size,
    float*       __restrict__ out)
{
    float s = 0.f;
    for (int i = threadIdx.x; i < MAIN_BLOCKS; i += 256) s += block_sums[i];
    #pragma unroll
    for (int off = 32; off > 0; off >>= 1) s += __shfl_xor(s, off);
    __shared__ float lds[4];
    if ((threadIdx.x & 63) == 0) lds[threadIdx.x >> 6] = s;
    __syncthreads();
    if (threadIdx.x == 0) {
        const float tot = lds[0] + lds[1] + lds[2] + lds[3];
        out[0] = -tot / (float)batch_size[0];
    }
}

extern "C" void kernel_launch(void* const* d_in, const int* in_sizes, int n_in,
                              void* d_out, int out_size, void* d_ws, size_t ws_size,
                              hipStream_t stream) {
    const float2* u_table   = (const float2*)d_in[0];
    const float2* v_table   = (const float2*)d_in[1];
    const int*    pos_u_idx = (const int*)d_in[2];
    const int*    pos_u_len = (const int*)d_in[3];
    const int*    pos_v_idx = (const int*)d_in[4];
    const int*    pos_v_len = (const int*)d_in[5];
    const int*    neg_v_idx = (const int*)d_in[6];
    const int*    neg_v_len = (const int*)d_in[7];
    const int*    batch_sz  = (const int*)d_in[8];

    float* block_sums = (float*)d_ws;   // MAIN_BLOCKS floats, every slot written

    skipgram_main<<<MAIN_BLOCKS, 256, 0, stream>>>(
        u_table, v_table, pos_u_idx, pos_u_len, pos_v_idx, pos_v_len,
        neg_v_idx, neg_v_len, block_sums);

    skipgram_reduce<<<1, 256, 0, stream>>>(block_sums, batch_sz, (float*)d_out);
}